// Round 1
// 223.252 us; speedup vs baseline: 1.0147x; 1.0147x over previous
//
#include <hip/hip_runtime.h>

// Quantized SiLU, S=8192 x H=4096, per-row scales.
//   x_f = x*sx[r]; y_q = clip(rint(sigmoid(x_f)/sy[r])); y_f = y_q*sy[r]
//   out = clip(rint(x_f*y_f/so[r]))
// Output float32 buffer: [S*H] values, then [S] scale_out copy.
//
// R2 change: x is int8-valued -> only 255 distinct inputs per row. The whole
// elementwise chain (expf + two IEEE divs, ~50 VALU ops/elem) collapses to a
// per-row 255-entry LUT built once per block by 255 threads, BIT-IDENTICAL to
// the R1-passing math (same ops, same order, computed once per value). Main
// loop becomes: nontemporal load -> LDS gather -> nontemporal store = pure
// memory-bound. LUT build latency hides under the 4 in-flight HBM loads.
//
// Numerics: y-path untouched (expf + two IEEE divs) — a y-flip in a row with
// s_y~s_o can cost ~|xf| (~6) quant steps. Final requant uses per-row
// reciprocal (flips there cost at most +-1, absmax stays 1.0).
// Nontemporal: x and out are each touched exactly once -> bypass cache alloc.

#define SEQ_LEN 8192
#define HIDDEN  4096
#define QMAX_F  127.0f
#define THREADS 256
#define VECS_PER_THREAD 4   // 256 thr * 4 vec * 4 elem = 4096 = one row

typedef int   iv4 __attribute__((ext_vector_type(4)));
typedef float fv4 __attribute__((ext_vector_type(4)));

__device__ __forceinline__ float silu_q_one(int xi, float s_x, float s_y,
                                            float r_o) {
    float xf  = (float)xi * s_x;                 // dequant (exact)
    float e   = expf(-xf);                       // ~1 ulp vs np.exp
    float sig = 1.0f / (1.0f + e);               // IEEE div (unchanged)
    float yq  = rintf(sig / s_y);                // IEEE div (unchanged)
    yq        = fminf(fmaxf(yq, -QMAX_F), QMAX_F);
    float yf  = yq * s_y;
    float of  = xf * yf;
    float oq  = rintf(of * r_o);                 // reciprocal-mul: flip cost <= 1
    return fminf(fmaxf(oq, -QMAX_F), QMAX_F);
}

__global__ __launch_bounds__(THREADS) void silu_quant_kernel(
    const int*   __restrict__ x,
    const float* __restrict__ scale_x,
    const float* __restrict__ scale_y,
    const float* __restrict__ scale_out,
    float*       __restrict__ out)
{
    __shared__ float lut[256];                   // 1 KB; entry = out value per int8 input

    const int row = blockIdx.x;                  // 8192 blocks, one per row
    const int t   = threadIdx.x;

    const iv4* __restrict__ xrow = (const iv4*)(x + (size_t)row * HIDDEN);
    fv4*       __restrict__ orow = (fv4*)(out + (size_t)row * HIDDEN);

    // Issue ALL global loads first: ~600-900 cy HBM latency covers the LUT
    // build's dependent expf/div chain for free.
    iv4 xv[VECS_PER_THREAD];
    #pragma unroll
    for (int k = 0; k < VECS_PER_THREAD; ++k)
        xv[k] = __builtin_nontemporal_load(xrow + t + k * THREADS);

    // Wave-uniform scalar loads (same address for all lanes in the block).
    const float s_x = scale_x[row];
    const float s_y = scale_y[row];
    const float s_o = scale_out[row];

    // 255 threads each evaluate ONE point of the per-row transfer function.
    // Identical ops to R1's per-element path -> bit-identical output.
    if (t < 255)
        lut[t] = silu_q_one(t - 127, s_x, s_y, 1.0f / s_o);

    // Tuple output #2: scale_out appended after the matrix (thread 255 so it
    // doesn't sit on the LUT-build critical path of wave 0).
    if (t == 255)
        out[(size_t)SEQ_LEN * HIDDEN + row] = s_o;

    __syncthreads();

    const float* lutc = lut + 127;               // index directly by xi in [-127,127]
    #pragma unroll
    for (int k = 0; k < VECS_PER_THREAD; ++k) {
        fv4 o;
        o.x = lutc[xv[k].x];
        o.y = lutc[xv[k].y];
        o.z = lutc[xv[k].z];
        o.w = lutc[xv[k].w];
        __builtin_nontemporal_store(o, orow + t + k * THREADS);
    }
}

extern "C" void kernel_launch(void* const* d_in, const int* in_sizes, int n_in,
                              void* d_out, int out_size, void* d_ws, size_t ws_size,
                              hipStream_t stream) {
    const int*   x         = (const int*)  d_in[0];
    const float* scale_x   = (const float*)d_in[1];
    const float* scale_y   = (const float*)d_in[2];
    const float* scale_out = (const float*)d_in[3];
    float*       out       = (float*)d_out;

    silu_quant_kernel<<<SEQ_LEN, THREADS, 0, stream>>>(
        x, scale_x, scale_y, scale_out, out);
}